// Round 5
// baseline (560.266 us; speedup 1.0000x reference)
//
#include <hip/hip_runtime.h>
#include <stdint.h>

// ---------------------------------------------------------------------------
// Binary (sign) weight 3-layer MLP, round 11:
//   prep (ONE kernel): binarize W1,W2,W3 + convert x f32->bf16 [65536,832]
//   gemm1: h1 = relu(Xp @ sign(W1)^T + b1) -> bf16 [65536,1024]
//   gemm2: h2 = relu(h1 @ sign(W2)^T + b2) -> bf16 [65536,512]
//   gemm3: out = h2 @ sign(W3)^T + b3      -> f32  [65536,10]
// R11 vs R10 (152us gemm1, MfmaUtil 31%, 2 blocks/CU of 8 waves):
//   Barrier-coupling fix: 128x128 tile, 4 waves (2x2), wave 64x64, dbuf LDS
//   32KB, regs 120 -> 4 BLOCKS/CU (16 waves, 4 independent barrier groups).
//   Loop = R9's proven 2-barrier counted-vmcnt structure (best measured),
//   vmcnt(4). Same swizzles/epilogue/XCD+K rotation.
// ---------------------------------------------------------------------------

typedef __attribute__((ext_vector_type(8))) short bf16x8;
typedef __attribute__((ext_vector_type(4))) float f32x4;

typedef const __attribute__((address_space(1))) unsigned int* as1_u32p;
typedef __attribute__((address_space(3))) unsigned int* as3_u32p;

__device__ __forceinline__ void glds16(const void* g, void* l) {
  __builtin_amdgcn_global_load_lds((as1_u32p)g, (as3_u32p)l, 16, 0, 0);
}

__device__ __forceinline__ unsigned short f2bf(float f) {
  union { float f; unsigned u; } c;
  c.f = f;
  unsigned u = c.u;
  u += 0x7FFFu + ((u >> 16) & 1u);  // RTNE
  return (unsigned short)(u >> 16);
}

__device__ __forceinline__ void binarize_one(const float* __restrict__ src,
                                             int Ns, int Ks, short* __restrict__ dst,
                                             int Kp, int idx, int total) {
  if (idx >= total) return;
  int n = idx / Kp;
  int k = idx - n * Kp;
  short v = 0;
  if (n < Ns && k < Ks)
    v = (src[n * Ks + k] >= 0.0f) ? (short)0x3F80 : (short)0xBF80;
  dst[idx] = v;
}

// ---------------------------------------------------------------------------
// prep: [0,26624) convert_x | binarize W1 (3328 blk) | W2 (2048) | W3 (32)
// ---------------------------------------------------------------------------
__global__ void prep_kernel(const float* __restrict__ X, short* __restrict__ Xp,
                            const float* __restrict__ W1, short* __restrict__ W1b,
                            const float* __restrict__ W2, short* __restrict__ W2b,
                            const float* __restrict__ W3, short* __restrict__ W3b) {
  constexpr int C0 = 26624;
  constexpr int C1 = C0 + 3328;
  constexpr int C2 = C1 + 2048;
  const int bid = blockIdx.x;
  if (bid < C0) {
    const int g = bid * 256 + threadIdx.x;
    const int row = g / 104;
    const int c = (g - row * 104) * 8;
    short tmp[8];
    if (c < 784) {
      const float* s = X + (size_t)row * 784 + c;
      float4 f0 = *(const float4*)s;
      float4 f1 = *(const float4*)(s + 4);
      tmp[0] = (short)f2bf(f0.x); tmp[1] = (short)f2bf(f0.y);
      tmp[2] = (short)f2bf(f0.z); tmp[3] = (short)f2bf(f0.w);
      tmp[4] = (short)f2bf(f1.x); tmp[5] = (short)f2bf(f1.y);
      tmp[6] = (short)f2bf(f1.z); tmp[7] = (short)f2bf(f1.w);
    } else {
#pragma unroll
      for (int i = 0; i < 8; ++i) tmp[i] = 0;
    }
    *(bf16x8*)(Xp + (size_t)row * 832 + c) = *(bf16x8*)(tmp);
  } else if (bid < C1) {
    binarize_one(W1, 1000, 784, W1b, 832, (bid - C0) * 256 + threadIdx.x, 1024 * 832);
  } else if (bid < C2) {
    binarize_one(W2, 500, 1000, W2b, 1024, (bid - C1) * 256 + threadIdx.x, 512 * 1024);
  } else {
    binarize_one(W3, 10, 500, W3b, 512, (bid - C2) * 256 + threadIdx.x, 16 * 512);
  }
}

// ---------------------------------------------------------------------------
// 128x128 tile, BK=32, 4 waves (2x2), wave out 64x64 (acc=64 AGPR).
// Dbuf LDS: A[2][128*32] + B[2][128*32] = 32 KiB -> 4 blocks/CU (16 waves).
// Per iter (R9 structure): frag-read(8 b128) -> 8 MFMA -> [lgkm0; barrier]
// -> stage it+2 into buf[pb] (4 glds) -> 8 MFMA -> [vmcnt(4); barrier].
// Swizzle: LDS[row][s] = global[row][s ^ ((row>>1)&3)], s = 8-short slot.
// ---------------------------------------------------------------------------
template <int KP, int NKT, int NP, int NR, int NT>
__global__ __launch_bounds__(256, 4)
void gemm128(const short* __restrict__ A, const short* __restrict__ Wb,
             const float* __restrict__ bias, short* __restrict__ Hout) {
  __shared__ short Abuf[2][128 * 32];
  __shared__ short Bbuf[2][128 * 32];

  // XCD swizzle: grid = 512*NT blocks (divisible by 8 -> bijective).
  constexpr int NWG8 = (512 * NT) >> 3;
  const int d = blockIdx.x;
  const int lid = (d & 7) * NWG8 + (d >> 3);
  const int mi = lid / NT;
  const int ni = lid - mi * NT;
  const int m0 = mi << 7;
  const int n0 = ni << 7;
  const int start = (ni * NKT) / NT;  // K-phase rotation

  const int tid = threadIdx.x;
  const int lane = tid & 63;
  const int w = tid >> 6;   // 0..3
  const int wm = w >> 1;    // 0..1  (64 m-rows)
  const int wn = w & 1;     // 0..1  (64 n-cols)
  const int l15 = lane & 15;
  const int quad = lane >> 4;

  // staging: 256 thr x 16B = 4KB/round = 64 rows x 64B. srow 0..63.
  const int srow = tid >> 2;
  const int gcol = (((tid & 3) ^ ((srow >> 1) & 3)) << 3);
  const short* ag = A + (size_t)(m0 + srow) * KP + gcol;
  const short* bg = Wb + (size_t)(n0 + srow) * KP + gcol;
  const int ldsw = w << 9;  // wave-uniform: w*512 shorts (16 rows x 32)

  auto stage = [&](int pb, int kit) {
    const short* sa = ag + kit * 32;
    const short* sb = bg + kit * 32;
    glds16(sa, &Abuf[pb][ldsw]);
    glds16(sa + (size_t)64 * KP, &Abuf[pb][ldsw + 2048]);
    glds16(sb, &Bbuf[pb][ldsw]);
    glds16(sb + (size_t)64 * KP, &Bbuf[pb][ldsw + 2048]);
  };

  // fragment read offsets: swizzle key (row>>1)&3 == (l15>>1)&3
  const int sl = (quad ^ ((l15 >> 1) & 3)) << 3;
  const int abase = ((wm << 6) + l15) * 32 + sl;   // + i*512
  const int bbase = ((wn << 6) + l15) * 32 + sl;   // + j*512

  f32x4 acc[4][4];
#pragma unroll
  for (int i = 0; i < 4; ++i)
#pragma unroll
    for (int j = 0; j < 4; ++j) acc[i][j] = (f32x4){0.f, 0.f, 0.f, 0.f};

  // prologue: stage tiles start -> buf0, start+1 -> buf1; confirm tile0
  int kt1 = start + 1; if (kt1 >= NKT) kt1 -= NKT;
  stage(0, start);
  stage(1, kt1);
  asm volatile("s_waitcnt vmcnt(4)" ::: "memory");
  __builtin_amdgcn_s_barrier();

  for (int it = 0; it < NKT; ++it) {
    const int pb = it & 1;
    const short* Ab = &Abuf[pb][0];
    const short* Bb = &Bbuf[pb][0];
    int kit2 = start + it + 2; if (kit2 >= NKT) kit2 -= NKT;
    const bool stg = (it + 2 < NKT);

    bf16x8 af[4], bf[4];
#pragma unroll
    for (int i = 0; i < 4; ++i) af[i] = *(const bf16x8*)(Ab + abase + i * 512);
#pragma unroll
    for (int j = 0; j < 4; ++j) bf[j] = *(const bf16x8*)(Bb + bbase + j * 512);

    // first MFMA half (i=0,1)
    __builtin_amdgcn_s_setprio(1);
#pragma unroll
    for (int i = 0; i < 2; ++i)
#pragma unroll
      for (int j = 0; j < 4; ++j)
        acc[i][j] = __builtin_amdgcn_mfma_f32_16x16x32_bf16(af[i], bf[j], acc[i][j], 0, 0, 0);
    __builtin_amdgcn_s_setprio(0);
    asm volatile("s_waitcnt lgkmcnt(0)" ::: "memory");  // my buf[pb] reads done
    __builtin_amdgcn_s_barrier();                       // all 4 waves done

    // stage tile it+2 into buf[pb] under second MFMA half
    if (stg) stage(pb, kit2);
    __builtin_amdgcn_s_setprio(1);
#pragma unroll
    for (int i = 2; i < 4; ++i)
#pragma unroll
      for (int j = 0; j < 4; ++j)
        acc[i][j] = __builtin_amdgcn_mfma_f32_16x16x32_bf16(af[i], bf[j], acc[i][j], 0, 0, 0);
    __builtin_amdgcn_s_setprio(0);
    // confirm tile it+1 resident; keep this iter's 4 glds in flight
    if (stg) asm volatile("s_waitcnt vmcnt(4)" ::: "memory");
    else     asm volatile("s_waitcnt vmcnt(0)" ::: "memory");
    __builtin_amdgcn_s_barrier();
  }

  // epilogue: j-innermost, both 32B halves of each 64B line adjacent
  float bv[4];
#pragma unroll
  for (int j = 0; j < 4; ++j) {
    const int n = n0 + (wn << 6) + (j << 4) + l15;
    bv[j] = (n < NR) ? bias[n] : 0.f;
  }
#pragma unroll
  for (int i = 0; i < 4; ++i) {
#pragma unroll
    for (int r = 0; r < 4; ++r) {
      const int mr = m0 + (wm << 6) + (i << 4) + (quad << 2) + r;
      short* rowp = Hout + (size_t)mr * NP + n0 + (wn << 6) + l15;
#pragma unroll
      for (int j = 0; j < 4; ++j) {
        float v = acc[i][j][r] + bv[j];
        v = v > 0.f ? v : 0.f;
        rowp[j << 4] = (short)f2bf(v);
      }
    }
  }
}

// ---------------------------------------------------------------------------
// Fallback GEMM1 (small-ws): fused fp32->bf16 convert, 128-tile, BK=32.
// ---------------------------------------------------------------------------
__global__ __launch_bounds__(256, 2)
void gemm1_fused_kernel(const float* __restrict__ X, const short* __restrict__ Wb,
                        const float* __restrict__ bias, short* __restrict__ H) {
  constexpr int K = 784, KP = 832, NP = 1024, NR = 1000;
  __shared__ short As[128 * 32];
  __shared__ short Bs[128 * 32];

  const int tid = threadIdx.x;
  const int lane = tid & 63;
  const int wave = tid >> 6;
  const int wm = wave >> 1, wn = wave & 1;
  const int l15 = lane & 15;
  const int quad = lane >> 4;
  const int m0 = blockIdx.y * 128;
  const int n0 = blockIdx.x * 128;

  const int ar = tid >> 1;
  const int aks = (tid & 1) * 16;
  const float* xrow = X + (size_t)(m0 + ar) * K;
  short* adst = As + ar * 32 + aks;

  const int br = wave * 16 + (lane >> 2);
  const int bks = (lane & 3) * 8;
  const short* brow0 = Wb + (size_t)(n0 + br) * KP + bks;
  short* bdst = Bs + (wave * 16) * 32;

  f32x4 acc[4][4];
#pragma unroll
  for (int i = 0; i < 4; ++i)
#pragma unroll
    for (int j2 = 0; j2 < 4; ++j2) acc[i][j2] = (f32x4){0.f, 0.f, 0.f, 0.f};

  for (int k0 = 0; k0 < KP; k0 += 32) {
    glds16(brow0 + k0, bdst);
    glds16(brow0 + k0 + (size_t)64 * KP, bdst + 64 * 32);
    short tmp[16];
#pragma unroll
    for (int c = 0; c < 4; ++c) {
      const int kk = k0 + aks + c * 4;
      float4 f;
      if (kk + 3 < K)
        f = *(const float4*)(xrow + kk);
      else
        f = make_float4(0.f, 0.f, 0.f, 0.f);
      tmp[c * 4 + 0] = (short)f2bf(f.x);
      tmp[c * 4 + 1] = (short)f2bf(f.y);
      tmp[c * 4 + 2] = (short)f2bf(f.z);
      tmp[c * 4 + 3] = (short)f2bf(f.w);
    }
    *(bf16x8*)(adst) = *(bf16x8*)(tmp);
    *(bf16x8*)(adst + 8) = *(bf16x8*)(tmp + 8);
    __syncthreads();

    const short* abase = As + (size_t)(wm * 64 + l15) * 32 + quad * 8;
    const short* bbase = Bs + (size_t)(wn * 64 + l15) * 32 + quad * 8;
    bf16x8 af[4], bfr[4];
#pragma unroll
    for (int i = 0; i < 4; ++i) af[i] = *(const bf16x8*)(abase + i * 16 * 32);
#pragma unroll
    for (int j2 = 0; j2 < 4; ++j2) bfr[j2] = *(const bf16x8*)(bbase + j2 * 16 * 32);
#pragma unroll
    for (int i = 0; i < 4; ++i)
#pragma unroll
      for (int j2 = 0; j2 < 4; ++j2)
        acc[i][j2] = __builtin_amdgcn_mfma_f32_16x16x32_bf16(af[i], bfr[j2], acc[i][j2], 0, 0, 0);
    __syncthreads();
  }

#pragma unroll
  for (int j2 = 0; j2 < 4; ++j2) {
    const int n = n0 + wn * 64 + j2 * 16 + l15;
    const float bv = (n < NR) ? bias[n] : 0.f;
#pragma unroll
    for (int i = 0; i < 4; ++i) {
      const int mr = m0 + wm * 64 + i * 16 + quad * 4;
#pragma unroll
      for (int r = 0; r < 4; ++r) {
        float v = acc[i][j2][r] + bv;
        v = v > 0.f ? v : 0.f;
        H[(size_t)(mr + r) * NP + n] = (short)f2bf(v);
      }
    }
  }
}

// ---------------------------------------------------------------------------
// GEMM3: h2 bf16 [65536,512] x W3b [16,512] -> out f32 [65536,10]
// ---------------------------------------------------------------------------
__global__ __launch_bounds__(256, 2)
void gemm3_kernel(const short* __restrict__ Hin, const short* __restrict__ Wb,
                  const float* __restrict__ bias, float* __restrict__ Out) {
  constexpr int KP = 512;
  __shared__ short As[64 * KP];

  const int tid = threadIdx.x;
  const int lane = tid & 63;
  const int wave = tid >> 6;
  const int l15 = lane & 15;
  const int quad = lane >> 4;
  const int m0 = blockIdx.x * 64;

  bf16x8 bw[16];
#pragma unroll
  for (int kk = 0; kk < 16; ++kk)
    bw[kk] = *(const bf16x8*)(Wb + l15 * KP + kk * 32 + quad * 8);

  const short* asrc = Hin + (size_t)(m0 + wave * 16) * KP + lane * 8;
  short* adst = As + (size_t)(wave * 16) * KP;
#pragma unroll
  for (int t = 0; t < 16; ++t)
    glds16(asrc + (size_t)t * KP, adst + (size_t)t * KP);

  __syncthreads();

  f32x4 acc = (f32x4){0.f, 0.f, 0.f, 0.f};
  const short* abase = As + (size_t)(wave * 16 + l15) * KP + quad * 8;
#pragma unroll
  for (int kk = 0; kk < 16; ++kk) {
    bf16x8 af = *(const bf16x8*)(abase + kk * 32);
    acc = __builtin_amdgcn_mfma_f32_16x16x32_bf16(af, bw[kk], acc, 0, 0, 0);
  }

  if (l15 < 10) {
    const float bv = bias[l15];
#pragma unroll
    for (int r = 0; r < 4; ++r) {
      const int mr = m0 + wave * 16 + quad * 4 + r;
      Out[(size_t)mr * 10 + l15] = acc[r] + bv;
    }
  }
}

// ---------------------------------------------------------------------------
extern "C" void kernel_launch(void* const* d_in, const int* in_sizes, int n_in,
                              void* d_out, int out_size, void* d_ws, size_t ws_size,
                              hipStream_t stream) {
  const float* x = (const float*)d_in[0];
  const float* W1 = (const float*)d_in[1];
  const float* b1 = (const float*)d_in[2];
  const float* W2 = (const float*)d_in[3];
  const float* b2 = (const float*)d_in[4];
  const float* W3 = (const float*)d_in[5];
  const float* b3 = (const float*)d_in[6];
  float* out = (float*)d_out;

  const size_t szW1 = (size_t)1024 * 832 * 2;
  const size_t szW2 = (size_t)512 * 1024 * 2;
  const size_t szW3 = (size_t)16 * 512 * 2;
  const size_t szH1 = (size_t)65536 * 1024 * 2;
  const size_t szXp = (size_t)65536 * 832 * 2;  // shares Z with h2
  const size_t need = szW1 + szW2 + szW3 + szH1 + szXp;  // ~246 MB

  uint8_t* p = (uint8_t*)d_ws;
  short* W1b = (short*)p; p += szW1;
  short* W2b = (short*)p; p += szW2;
  short* W3b = (short*)p; p += szW3;
  short* h1 = (short*)p; p += szH1;
  short* Z = (short*)p;  // Xp (prep+gemm1), then h2 (gemm2+gemm3)

  if (ws_size >= need) {
    short* Xp = Z;
    short* h2 = Z;
    prep_kernel<<<26624 + 3328 + 2048 + 32, 256, 0, stream>>>(
        x, Xp, W1, W1b, W2, W2b, W3, W3b);
    gemm128<832, 26, 1024, 1000, 8><<<4096, 256, 0, stream>>>(Xp, W1b, b1, h1);
    gemm128<1024, 32, 512, 500, 4><<<2048, 256, 0, stream>>>(h1, W2b, b2, h2);
    gemm3_kernel<<<1024, 256, 0, stream>>>(h2, W3b, b3, out);
  } else {
    short* h2 = Z;
    prep_kernel<<<26624 + 3328 + 2048 + 32, 256, 0, stream>>>(
        x, Z, W1, W1b, W2, W2b, W3, W3b);
    gemm1_fused_kernel<<<dim3(8, 512), 256, 0, stream>>>(x, W1b, b1, h1);
    gemm128<1024, 32, 512, 500, 4><<<2048, 256, 0, stream>>>(h1, W2b, b2, h2);
    gemm3_kernel<<<1024, 256, 0, stream>>>(h2, W3b, b3, out);
  }
}